// Round 3
// baseline (4046.074 us; speedup 1.0000x reference)
//
#include <hip/hip_runtime.h>
#include <hip/hip_bf16.h>
#include <hip/hip_fp16.h>
#include <math.h>

#define Bdim 128
#define Tdim 96
#define Fdim 64
#define Sdim 16
#define Rdim 6
#define KACT 4
#define Hdim 128
#define DK 64
#define DV 128
#define HC 4
#define CK 32
#define CV 32

#define SPIN_BOUND (1u << 17)

__device__ __forceinline__ float sigmoidf_(float x) { return 1.0f / (1.0f + expf(-x)); }

// ---------------- Kernel 1: precompute gamma_h, k, v for all (b,t) ----------------
__global__ __launch_bounds__(128) void k_pre(
    const float* __restrict__ x, const float* __restrict__ mask,
    const float* __restrict__ delta, const float* __restrict__ xlast,
    const float* __restrict__ xmean,
    const float* __restrict__ Wgx, const float* __restrict__ bgx,
    const float* __restrict__ Wgh, const float* __restrict__ bgh,
    const float* __restrict__ Wk, const float* __restrict__ bk,
    const float* __restrict__ Wv, const float* __restrict__ bv,
    float* __restrict__ ghO, float* __restrict__ kO, float* __restrict__ vO)
{
    const int bt = blockIdx.x;
    const int b = bt / Tdim, t = bt % Tdim;
    const int tid = threadIdx.x;
    __shared__ float d_s[Fdim], xh_s[Fdim];
    const int base = (b * Tdim + t) * Fdim;

    if (tid < Fdim) d_s[tid] = delta[base + tid];
    __syncthreads();

    if (tid < Fdim) {
        float z = bgx[tid];
        #pragma unroll 8
        for (int i = 0; i < Fdim; ++i) z += d_s[i] * Wgx[i * Fdim + tid];
        float gx = expf(-fmaxf(z, 0.0f));
        float m = mask[base + tid], xv = x[base + tid];
        float xl = xlast[base + tid], xm = xmean[b * Fdim + tid];
        xh_s[tid] = m * xv + (1.0f - m) * (gx * xl + (1.0f - gx) * xm);
    }
    {
        float z = bgh[tid];
        #pragma unroll 8
        for (int i = 0; i < Fdim; ++i) z += d_s[i] * Wgh[i * Hdim + tid];
        ghO[(size_t)(b * Tdim + t) * Hdim + tid] = expf(-fmaxf(z, 0.0f));
    }
    __syncthreads();

    if (tid < DK) {
        float z = bk[tid];
        #pragma unroll 8
        for (int j = 0; j < Fdim; ++j) z += xh_s[j] * Wk[j * DK + tid];
        kO[(size_t)(b * Tdim + t) * DK + tid] = z;
    }
    {
        float z = bv[tid];
        #pragma unroll 8
        for (int j = 0; j < Fdim; ++j) z += xh_s[j] * Wv[j * DV + tid];
        vO[(size_t)(b * Tdim + t) * DV + tid] = z;
    }
}

// ---------------- Kernel 1b: BX[r,c] = bv @ Wx_rnn[r];  WB[r,h] = Wq_in[r,h,:]·bk ----------------
__global__ __launch_bounds__(256) void k_bx(
    const float* __restrict__ bv, const float* __restrict__ Wx_rnn,
    const float* __restrict__ bk, const float* __restrict__ Wq_in,
    float* __restrict__ BX, float* __restrict__ WB)
{
    int c = blockIdx.x * 256 + threadIdx.x;
    if (c < Rdim * 512) {
        int r = c >> 9, cc = c & 511;
        float acc = 0.0f;
        #pragma unroll 4
        for (int d = 0; d < DV; ++d)
            acc += bv[d] * Wx_rnn[((size_t)r * DV + d) * 512 + cc];
        BX[c] = acc;
    } else if (c < Rdim * 512 + Rdim * Hdim) {
        int i = c - Rdim * 512;
        int r = i >> 7, h = i & 127;
        float acc = 0.0f;
        #pragma unroll 8
        for (int d = 0; d < DK; ++d)
            acc += Wq_in[((size_t)r * Hdim + h) * DK + d] * bk[d];
        WB[i] = acc;
    }
}

// ---------------- Kernel 1c: VX[b,t,r,c] = v[b,t,:] @ Wx_rnn[r][:,c] ----------------
#define VX_BT 32
__global__ __launch_bounds__(256) void k_vx(
    const float* __restrict__ vG, const float* __restrict__ Wx_rnn,
    float* __restrict__ VX32, __half* __restrict__ VX16, const int m16)
{
    const int bt0 = blockIdx.x * VX_BT;
    const int r = blockIdx.y;
    const int c = blockIdx.z * 128 + (threadIdx.x & 127);
    const int half = threadIdx.x >> 7;
    __shared__ float vv_s[VX_BT][DV];

    for (int i = threadIdx.x; i < VX_BT * DV; i += 256)
        vv_s[i >> 7][i & 127] = vG[(size_t)(bt0 + (i >> 7)) * DV + (i & 127)];
    __syncthreads();

    float acc[16];
    #pragma unroll
    for (int i = 0; i < 16; ++i) acc[i] = 0.0f;

    const float* wp = Wx_rnn + ((size_t)r * DV) * 512 + c;
    const int btb = half * 16;
    #pragma unroll 4
    for (int d = 0; d < DV; ++d) {
        float w = wp[(size_t)d * 512];
        #pragma unroll
        for (int i = 0; i < 16; ++i) acc[i] += vv_s[btb + i][d] * w;
    }
    #pragma unroll
    for (int i = 0; i < 16; ++i) {
        size_t idx = ((size_t)(bt0 + btb + i) * Rdim + r) * 512 + c;
        if (m16) VX16[idx] = __float2half(acc[i]);
        else     VX32[idx] = acc[i];
    }
}

// ---------------- Kernel 1d: WK[bt,r,h] = Wq_in[r,h,:] · k[bt,:] ----------------
__global__ __launch_bounds__(256) void k_wk(
    const float* __restrict__ kG, const float* __restrict__ Wq_in,
    float* __restrict__ WK)
{
    const int bt0 = blockIdx.x * 32;
    const int r = blockIdx.y;
    __shared__ float ks[32][66];
    for (int e = threadIdx.x; e < 32 * 64; e += 256)
        ks[e >> 6][e & 63] = kG[(size_t)(bt0 + (e >> 6)) * DK + (e & 63)];
    __syncthreads();

    const int btl = threadIdx.x >> 3, hg = threadIdx.x & 7;
    const float* wq = Wq_in + (size_t)r * Hdim * DK;
    #pragma unroll 4
    for (int i = 0; i < 16; ++i) {
        int h = hg + i * 8;
        const float4* wr = (const float4*)(wq + (size_t)h * DK);
        float acc = 0.0f;
        #pragma unroll
        for (int d4 = 0; d4 < 16; ++d4) {
            float4 w = wr[d4];
            acc += w.x * ks[btl][d4 * 4] + w.y * ks[btl][d4 * 4 + 1]
                 + w.z * ks[btl][d4 * 4 + 2] + w.w * ks[btl][d4 * 4 + 3];
        }
        WK[((size_t)(bt0 + btl) * Rdim + r) * Hdim + h] = acc;
    }
}

// ---------------- Kernel 2: sequential scan; 2 blocks per batch element (3 units each) ----------------
__global__ __launch_bounds__(768) void k_seq(
    const float* __restrict__ h0, const float* __restrict__ c0,
    const float* __restrict__ Wh_rnn, const float* __restrict__ b_rnn,
    const float* __restrict__ Wq_c, const float* __restrict__ Wk_c,
    const float* __restrict__ Wv_c, const float* __restrict__ Wout_c,
    const float* __restrict__ ghG,
    const float* __restrict__ WK, const float* __restrict__ WB,
    const float* __restrict__ VX32, const __half* __restrict__ VX16, const int m16,
    const float* __restrict__ BX,
    unsigned* __restrict__ flags, float* __restrict__ ex,
    float* __restrict__ hs_fin)
{
    const int b    = blockIdx.x & 127;
    const int half = blockIdx.x >> 7;
    const int rb   = half * 3;
    const int orb  = (1 - half) * 3;
    const int tid  = threadIdx.x;

    __shared__ float hs[3][Hdim], cs[3][Hdim], hn[3][Hdim], cn[3][Hdim];
    __shared__ float partial[2][1536];
    __shared__ float qc[3][Hdim], kc_all[Rdim][Hdim], vc_all[Rdim][Hdim], ctx[3][Hdim];
    __shared__ float gh_s[Hdim];
    __shared__ float s0_all[8], p0o[4], p1o[4], mk[8];
    __shared__ float scs[HC][3][Rdim], cps[HC][3][Rdim];

    unsigned* fA  = flags + (b * 2 + half) * 16;
    unsigned* fAo = flags + (b * 2 + (1 - half)) * 16;
    unsigned* fB  = flags + 4096 + (b * 2 + half) * 16;
    unsigned* fBo = flags + 4096 + (b * 2 + (1 - half)) * 16;
    float* exb = ex + (size_t)b * 4096;

    if (tid < 384) {
        int rl = tid >> 7, j = tid & 127;
        hs[rl][j] = h0[(size_t)b * 768 + (rb + rl) * 128 + j];
        cs[rl][j] = c0[(size_t)b * 768 + (rb + rl) * 128 + j];
    }
    __syncthreads();

    for (int t = 0; t < Tdim; ++t) {
        const int bt = b * Tdim + t;
        const int par = t & 1;

        // A: load gamma_h, decay own hs rows
        if (tid < 128) gh_s[tid] = ghG[(size_t)bt * Hdim + tid];
        __syncthreads();
        if (tid < 384) { int rl = tid >> 7, j = tid & 127; hs[rl][j] *= gh_s[j]; }
        __syncthreads();

        // B: scores for own 3 units (waves 0..2), probs; export s0
        if (tid < 192) {
            int w = tid >> 6, l = tid & 63;
            const float* wk = WK + ((size_t)bt * Rdim + rb + w) * Hdim;
            const float* wb = WB + (rb + w) * Hdim;
            float hv0 = hs[w][l], hv1 = hs[w][l + 64];
            float a0 = hv0 * wk[l] + hv1 * wk[l + 64];
            float a1 = hv0 * wb[l] + hv1 * wb[l + 64];
            #pragma unroll
            for (int off = 32; off > 0; off >>= 1) {
                a0 += __shfl_xor(a0, off);
                a1 += __shfl_xor(a1, off);
            }
            if (l == 0) {
                float sv0 = a0 * 0.125f, sv1 = a1 * 0.125f;
                s0_all[rb + w] = sv0;
                float m = fmaxf(sv0, sv1);
                float e0 = expf(sv0 - m), e1 = expf(sv1 - m);
                float inv = 1.0f / (e0 + e1);
                p0o[w] = e0 * inv; p1o[w] = e1 * inv;
                __hip_atomic_store((unsigned*)(exb + (half * 2 + par) * 4) + w,
                                   __float_as_uint(sv0),
                                   __ATOMIC_RELAXED, __HIP_MEMORY_SCOPE_AGENT);
            }
        }
        __syncthreads();   // drains vmcnt -> s0 stores visible
        if (tid == 0)
            __hip_atomic_store(fA, (unsigned)(t + 1), __ATOMIC_RELEASE, __HIP_MEMORY_SCOPE_AGENT);

        // E: pre = p0*VX + p1*BX + b + hs@Wh, 2-way K-split
        {
            int kh = (tid >= 384) ? 1 : 0, g = tid - kh * 384;
            int o = g * 4, rl = o >> 9, c = o & 511;
            const float* wh = Wh_rnn + ((size_t)(rb + rl) * Hdim + kh * 64) * 512 + c;
            float4 acc = make_float4(0.f, 0.f, 0.f, 0.f);
            if (!kh) {
                float P0 = p0o[rl], P1 = p1o[rl];
                float4 bx = *(const float4*)(BX + (rb + rl) * 512 + c);
                float4 bb = *(const float4*)(b_rnn + (rb + rl) * 512 + c);
                if (m16) {
                    const __half2* vp = (const __half2*)(VX16 + ((size_t)bt * Rdim + rb + rl) * 512 + c);
                    float2 v01 = __half22float2(vp[0]), v23 = __half22float2(vp[1]);
                    acc.x = bb.x + P0 * v01.x + P1 * bx.x;
                    acc.y = bb.y + P0 * v01.y + P1 * bx.y;
                    acc.z = bb.z + P0 * v23.x + P1 * bx.z;
                    acc.w = bb.w + P0 * v23.y + P1 * bx.w;
                } else {
                    float4 vx = *(const float4*)(VX32 + ((size_t)bt * Rdim + rb + rl) * 512 + c);
                    acc.x = bb.x + P0 * vx.x + P1 * bx.x;
                    acc.y = bb.y + P0 * vx.y + P1 * bx.y;
                    acc.z = bb.z + P0 * vx.z + P1 * bx.z;
                    acc.w = bb.w + P0 * vx.w + P1 * bx.w;
                }
            }
            const float* hrow = &hs[rl][kh * 64];
            #pragma unroll 8
            for (int d = 0; d < 64; ++d) {
                float hd = hrow[d];
                float4 w = *(const float4*)(wh + (size_t)d * 512);
                acc.x += hd * w.x; acc.y += hd * w.y;
                acc.z += hd * w.z; acc.w += hd * w.w;
            }
            *(float4*)&partial[kh][o] = acc;
        }
        __syncthreads();

        // F: LSTM elementwise
        if (tid < 384) {
            int rl = tid >> 7, j = tid & 127;
            int base = rl * 512;
            float ig = partial[0][base + j]       + partial[1][base + j];
            float fg = partial[0][base + 128 + j] + partial[1][base + 128 + j];
            float gg = partial[0][base + 256 + j] + partial[1][base + 256 + j];
            float og = partial[0][base + 384 + j] + partial[1][base + 384 + j];
            float cnew = sigmoidf_(fg) * cs[rl][j] + sigmoidf_(ig) * tanhf(gg);
            float hnew = sigmoidf_(og) * tanhf(cnew);
            cn[rl][j] = cnew; hn[rl][j] = hnew;
        }
        __syncthreads();

        // G: qc/kc/vc for own units, 2-way K-split
        if (tid < 576) {
            int kh = (tid >= 288) ? 1 : 0, g = tid - kh * 288;
            int o = g * 4;
            int rl = o / 384, cc = o % 384, mId = cc >> 7, col = cc & 127;
            const float* Wm = (mId == 0 ? Wq_c : (mId == 1 ? Wk_c : Wv_c))
                              + ((size_t)(rb + rl) * Hdim + kh * 64) * Hdim + col;
            const float* hrow = &hn[rl][kh * 64];
            float4 acc = make_float4(0.f, 0.f, 0.f, 0.f);
            #pragma unroll 8
            for (int d = 0; d < 64; ++d) {
                float hd = hrow[d];
                float4 w = *(const float4*)(Wm + (size_t)d * Hdim);
                acc.x += hd * w.x; acc.y += hd * w.y;
                acc.z += hd * w.z; acc.w += hd * w.w;
            }
            *(float4*)&partial[kh][o] = acc;
        }
        __syncthreads();
        if (tid < 576) {
            #pragma unroll
            for (int rep = 0; rep < 2; ++rep) {
                int o = tid * 2 + rep;
                float v = partial[0][o] + partial[1][o];
                int rl = o / 384, cc = o % 384, mId = cc >> 7, col = cc & 127;
                if (mId == 0) qc[rl][col] = v;
                else if (mId == 1) kc_all[rb + rl][col] = v;
                else vc_all[rb + rl][col] = v;
            }
        }
        __syncthreads();
        // export own kc/vc
        {
            int rl = tid / 256, rest = tid % 256, which = rest >> 7, col = rest & 127;
            float v = (which == 0) ? kc_all[rb + rl][col] : vc_all[rb + rl][col];
            __hip_atomic_store((unsigned*)(exb + 64 + (half * 2 + par) * 768) + tid,
                               __float_as_uint(v),
                               __ATOMIC_RELAXED, __HIP_MEMORY_SCOPE_AGENT);
        }
        __syncthreads();   // drains vmcnt
        if (tid == 0) {
            __hip_atomic_store(fB, (unsigned)(t + 1), __ATOMIC_RELEASE, __HIP_MEMORY_SCOPE_AGENT);
            unsigned it = 0;
            while (__hip_atomic_load(fAo, __ATOMIC_ACQUIRE, __HIP_MEMORY_SCOPE_AGENT) < (unsigned)(t + 1)
                   && ++it < SPIN_BOUND) {}
            const unsigned* so = (const unsigned*)(exb + ((1 - half) * 2 + par) * 4);
            for (int j = 0; j < 3; ++j)
                s0_all[orb + j] = __uint_as_float(
                    __hip_atomic_load(so + j, __ATOMIC_RELAXED, __HIP_MEMORY_SCOPE_AGENT));
            it = 0;
            while (__hip_atomic_load(fBo, __ATOMIC_ACQUIRE, __HIP_MEMORY_SCOPE_AGENT) < (unsigned)(t + 1)
                   && ++it < SPIN_BOUND) {}
        }
        __syncthreads();
        // import other's kc/vc; compute top-k mask
        {
            int rl = tid / 256, rest = tid % 256, which = rest >> 7, col = rest & 127;
            const unsigned* kv = (const unsigned*)(exb + 64 + ((1 - half) * 2 + par) * 768);
            float v = __uint_as_float(
                __hip_atomic_load(kv + tid, __ATOMIC_RELAXED, __HIP_MEMORY_SCOPE_AGENT));
            if (which == 0) kc_all[orb + rl][col] = v; else vc_all[orb + rl][col] = v;
        }
        if (tid < 6) {
            int rank = 0;
            #pragma unroll
            for (int j = 0; j < 6; ++j)
                rank += (s0_all[j] > s0_all[tid] || (s0_all[j] == s0_all[tid] && j < tid)) ? 1 : 0;
            mk[tid] = (rank < KACT) ? 1.0f : 0.0f;
        }
        __syncthreads();

        // H: attention scores (own rr x all ss x heads)
        if (tid < 72) {
            int rr = tid / 24, ss = (tid % 24) >> 2, h = tid & 3;
            float acc = 0.0f;
            #pragma unroll 8
            for (int d = 0; d < CK; ++d) acc += qc[rr][h * 32 + d] * kc_all[ss][h * 32 + d];
            scs[h][rr][ss] = acc * 0.17677669529663687f;
        }
        __syncthreads();

        // I: softmax * mask
        if (tid < 12) {
            int rr = tid >> 2, h = tid & 3;
            float m = scs[h][rr][0];
            #pragma unroll
            for (int ss = 1; ss < 6; ++ss) m = fmaxf(m, scs[h][rr][ss]);
            float e[6], sum = 0.0f;
            #pragma unroll
            for (int ss = 0; ss < 6; ++ss) { e[ss] = expf(scs[h][rr][ss] - m); sum += e[ss]; }
            float inv = mk[rb + rr] / sum;
            #pragma unroll
            for (int ss = 0; ss < 6; ++ss) cps[h][rr][ss] = e[ss] * inv;
        }
        __syncthreads();

        // J: ctx
        if (tid < 384) {
            int rr = tid >> 7, e = tid & 127, h = e >> 5;
            float acc = 0.0f;
            #pragma unroll
            for (int ss = 0; ss < 6; ++ss) acc += cps[h][rr][ss] * vc_all[ss][e];
            ctx[rr][e] = acc;
        }
        __syncthreads();

        // K: Wout for active own rows, 2-way K-split
        if (tid < 192) {
            int kh = (tid >= 96) ? 1 : 0, g = tid - kh * 96;
            int o = g * 4, rl = o >> 7, col = o & 127;
            if (mk[rb + rl] > 0.5f) {
                const float* wo = Wout_c + ((size_t)(rb + rl) * Hdim + kh * 64) * Hdim + col;
                const float* crow = &ctx[rl][kh * 64];
                float4 acc = make_float4(0.f, 0.f, 0.f, 0.f);
                #pragma unroll 8
                for (int d = 0; d < 64; ++d) {
                    float ce = crow[d];
                    float4 w = *(const float4*)(wo + (size_t)d * Hdim);
                    acc.x += ce * w.x; acc.y += ce * w.y;
                    acc.z += ce * w.z; acc.w += ce * w.w;
                }
                *(float4*)&partial[kh][o] = acc;
            }
        }
        __syncthreads();
        if (tid < 384) {
            int rl = tid >> 7, j = tid & 127;
            if (mk[rb + rl] > 0.5f) {
                cs[rl][j] = cn[rl][j];
                hs[rl][j] = partial[0][rl * 128 + j] + partial[1][rl * 128 + j] + hn[rl][j];
            }
        }
        __syncthreads();
    }

    if (tid < 384) {
        int rl = tid >> 7, j = tid & 127;
        hs_fin[(size_t)b * 768 + (rb + rl) * 128 + j] = hs[rl][j];
    }
}

// ---------------- Kernel 3: head ----------------
__global__ __launch_bounds__(64) void k_head(
    const float* __restrict__ hs_fin, const float* __restrict__ statics,
    const float* __restrict__ W1, const float* __restrict__ b1,
    const float* __restrict__ W2, const float* __restrict__ b2,
    float* __restrict__ out)
{
    const int b = blockIdx.x, tid = threadIdx.x;
    float a = b1[tid];
    const float* hsf = hs_fin + (size_t)b * 768;
    #pragma unroll 4
    for (int i = 0; i < Rdim * Hdim; ++i) a += hsf[i] * W1[i * 64 + tid];
    #pragma unroll
    for (int i = 0; i < Sdim; ++i) a += statics[b * Sdim + i] * W1[(Rdim * Hdim + i) * 64 + tid];
    float pv = a * W2[tid];
    #pragma unroll
    for (int off = 32; off > 0; off >>= 1) pv += __shfl_xor(pv, off);
    if (tid == 0) out[b] = pv + b2[0];
}

extern "C" void kernel_launch(void* const* d_in, const int* in_sizes, int n_in,
                              void* d_out, int out_size, void* d_ws, size_t ws_size,
                              hipStream_t stream) {
    const float* x       = (const float*)d_in[0];
    const float* statics = (const float*)d_in[1];
    const float* mask    = (const float*)d_in[2];
    const float* delta   = (const float*)d_in[3];
    const float* xlast   = (const float*)d_in[4];
    const float* xmean   = (const float*)d_in[5];
    const float* h0      = (const float*)d_in[6];
    const float* c0      = (const float*)d_in[7];
    const float* Wgx     = (const float*)d_in[8];
    const float* bgx     = (const float*)d_in[9];
    const float* Wgh     = (const float*)d_in[10];
    const float* bgh     = (const float*)d_in[11];
    const float* Wk_in   = (const float*)d_in[12];
    const float* bk_in   = (const float*)d_in[13];
    const float* Wv_in   = (const float*)d_in[14];
    const float* bv_in   = (const float*)d_in[15];
    const float* Wq_in   = (const float*)d_in[16];
    const float* Wx_rnn  = (const float*)d_in[17];
    const float* Wh_rnn  = (const float*)d_in[18];
    const float* b_rnn   = (const float*)d_in[19];
    const float* Wq_c    = (const float*)d_in[20];
    const float* Wk_c    = (const float*)d_in[21];
    const float* Wv_c    = (const float*)d_in[22];
    const float* Wout_c  = (const float*)d_in[23];
    const float* W1      = (const float*)d_in[24];
    const float* b1      = (const float*)d_in[25];
    const float* W2      = (const float*)d_in[26];
    const float* b2      = (const float*)d_in[27];

    const size_t nGh = (size_t)Bdim * Tdim * Hdim;       // 1,179,648
    const size_t nK  = (size_t)Bdim * Tdim * DK;         //   786,432
    const size_t nV  = (size_t)Bdim * Tdim * DV;         // 1,572,864
    const size_t nBX = (size_t)Rdim * 512;               //     3,072
    const size_t nWB = (size_t)Rdim * Hdim;              //       768
    const size_t nWK = (size_t)Bdim * Tdim * Rdim * Hdim;// 9,437,184
    const size_t nVX = (size_t)Bdim * Tdim * Rdim * 512; // 37,748,736

    float* ws  = (float*)d_ws;
    float* ghG = ws;
    float* kG  = ghG + nGh;
    float* vG  = kG + nK;
    float* BX  = vG + nV;
    float* WB  = BX + nBX;
    float* WK  = WB + nWB;
    float* VXf = WK + nWK;                   // f32 VX (or halfs in same region)
    __half* VXh = (__half*)VXf;

    const size_t base = nGh + nK + nV + nBX + nWB + nWK;
    const int m16 = (ws_size >= (base + nVX) * sizeof(float)) ? 0 : 1;

    // overlay inside vG region (only live after k_vx has consumed vG):
    unsigned* flags  = (unsigned*)vG;                 // 8192 uints (32 KB)
    float*    ex     = vG + 8192;                     // 128 * 4096 floats
    float*    hs_fin = vG + 8192 + (size_t)Bdim * 4096;

    k_pre<<<dim3(Bdim * Tdim), dim3(128), 0, stream>>>(
        x, mask, delta, xlast, xmean, Wgx, bgx, Wgh, bgh,
        Wk_in, bk_in, Wv_in, bv_in, ghG, kG, vG);

    k_bx<<<dim3((Rdim * 512 + Rdim * Hdim + 255) / 256), dim3(256), 0, stream>>>(
        bv_in, Wx_rnn, bk_in, Wq_in, BX, WB);

    k_wk<<<dim3(Bdim * Tdim / 32, Rdim), dim3(256), 0, stream>>>(kG, Wq_in, WK);

    k_vx<<<dim3(Bdim * Tdim / VX_BT, Rdim, 4), dim3(256), 0, stream>>>(
        vG, Wx_rnn, VXf, VXh, m16);

    hipMemsetAsync(flags, 0, 8192 * sizeof(unsigned), stream);

    k_seq<<<dim3(2 * Bdim), dim3(768), 0, stream>>>(
        h0, c0, Wh_rnn, b_rnn, Wq_c, Wk_c, Wv_c, Wout_c,
        ghG, WK, WB, VXf, VXh, m16, BX, flags, ex, hs_fin);

    k_head<<<dim3(Bdim), dim3(64), 0, stream>>>(
        hs_fin, statics, W1, b1, W2, b2, (float*)d_out);
}

// Round 4
// 3320.013 us; speedup vs baseline: 1.2187x; 1.2187x over previous
//
#include <hip/hip_runtime.h>
#include <hip/hip_bf16.h>
#include <hip/hip_fp16.h>
#include <math.h>

#define Bdim 128
#define Tdim 96
#define Fdim 64
#define Sdim 16
#define Rdim 6
#define KACT 4
#define Hdim 128
#define DK 64
#define DV 128
#define HC 4
#define CK 32
#define CV 32

__device__ __forceinline__ float sigmoidf_(float x) { return 1.0f / (1.0f + expf(-x)); }

// ---------------- Kernel 1: precompute gamma_h, k, v for all (b,t) ----------------
__global__ __launch_bounds__(128) void k_pre(
    const float* __restrict__ x, const float* __restrict__ mask,
    const float* __restrict__ delta, const float* __restrict__ xlast,
    const float* __restrict__ xmean,
    const float* __restrict__ Wgx, const float* __restrict__ bgx,
    const float* __restrict__ Wgh, const float* __restrict__ bgh,
    const float* __restrict__ Wk, const float* __restrict__ bk,
    const float* __restrict__ Wv, const float* __restrict__ bv,
    float* __restrict__ ghO, float* __restrict__ kO, float* __restrict__ vO)
{
    const int bt = blockIdx.x;
    const int b = bt / Tdim, t = bt % Tdim;
    const int tid = threadIdx.x;
    __shared__ float d_s[Fdim], xh_s[Fdim];
    const int base = (b * Tdim + t) * Fdim;

    if (tid < Fdim) d_s[tid] = delta[base + tid];
    __syncthreads();

    if (tid < Fdim) {
        float z = bgx[tid];
        #pragma unroll 8
        for (int i = 0; i < Fdim; ++i) z += d_s[i] * Wgx[i * Fdim + tid];
        float gx = expf(-fmaxf(z, 0.0f));
        float m = mask[base + tid], xv = x[base + tid];
        float xl = xlast[base + tid], xm = xmean[b * Fdim + tid];
        xh_s[tid] = m * xv + (1.0f - m) * (gx * xl + (1.0f - gx) * xm);
    }
    {
        float z = bgh[tid];
        #pragma unroll 8
        for (int i = 0; i < Fdim; ++i) z += d_s[i] * Wgh[i * Hdim + tid];
        ghO[(size_t)(b * Tdim + t) * Hdim + tid] = expf(-fmaxf(z, 0.0f));
    }
    __syncthreads();

    if (tid < DK) {
        float z = bk[tid];
        #pragma unroll 8
        for (int j = 0; j < Fdim; ++j) z += xh_s[j] * Wk[j * DK + tid];
        kO[(size_t)(b * Tdim + t) * DK + tid] = z;
    }
    {
        float z = bv[tid];
        #pragma unroll 8
        for (int j = 0; j < Fdim; ++j) z += xh_s[j] * Wv[j * DV + tid];
        vO[(size_t)(b * Tdim + t) * DV + tid] = z;
    }
}

// ---------------- Kernel 1b: BX[r,c] = bv @ Wx_rnn[r];  WB[r,h] = Wq_in[r,h,:]·bk ----------------
__global__ __launch_bounds__(256) void k_bx(
    const float* __restrict__ bv, const float* __restrict__ Wx_rnn,
    const float* __restrict__ bk, const float* __restrict__ Wq_in,
    float* __restrict__ BX, float* __restrict__ WB)
{
    int c = blockIdx.x * 256 + threadIdx.x;
    if (c < Rdim * 512) {
        int r = c >> 9, cc = c & 511;
        float acc = 0.0f;
        #pragma unroll 4
        for (int d = 0; d < DV; ++d)
            acc += bv[d] * Wx_rnn[((size_t)r * DV + d) * 512 + cc];
        BX[c] = acc;
    } else if (c < Rdim * 512 + Rdim * Hdim) {
        int i = c - Rdim * 512;
        int r = i >> 7, h = i & 127;
        float acc = 0.0f;
        #pragma unroll 8
        for (int d = 0; d < DK; ++d)
            acc += Wq_in[((size_t)r * Hdim + h) * DK + d] * bk[d];
        WB[i] = acc;
    }
}

// ---------------- Kernel 1c: VX[b,t,r,c] = v[b,t,:] @ Wx_rnn[r][:,c] ----------------
#define VX_BT 32
__global__ __launch_bounds__(256) void k_vx(
    const float* __restrict__ vG, const float* __restrict__ Wx_rnn,
    float* __restrict__ VX32, __half* __restrict__ VX16, const int m16)
{
    const int bt0 = blockIdx.x * VX_BT;
    const int r = blockIdx.y;
    const int c = blockIdx.z * 128 + (threadIdx.x & 127);
    const int half = threadIdx.x >> 7;
    __shared__ float vv_s[VX_BT][DV];

    for (int i = threadIdx.x; i < VX_BT * DV; i += 256)
        vv_s[i >> 7][i & 127] = vG[(size_t)(bt0 + (i >> 7)) * DV + (i & 127)];
    __syncthreads();

    float acc[16];
    #pragma unroll
    for (int i = 0; i < 16; ++i) acc[i] = 0.0f;

    const float* wp = Wx_rnn + ((size_t)r * DV) * 512 + c;
    const int btb = half * 16;
    #pragma unroll 4
    for (int d = 0; d < DV; ++d) {
        float w = wp[(size_t)d * 512];
        #pragma unroll
        for (int i = 0; i < 16; ++i) acc[i] += vv_s[btb + i][d] * w;
    }
    #pragma unroll
    for (int i = 0; i < 16; ++i) {
        size_t idx = ((size_t)(bt0 + btb + i) * Rdim + r) * 512 + c;
        if (m16) VX16[idx] = __float2half(acc[i]);
        else     VX32[idx] = acc[i];
    }
}

// ---------------- Kernel 1d: WK[bt,r,h] = Wq_in[r,h,:] · k[bt,:] ----------------
__global__ __launch_bounds__(256) void k_wk(
    const float* __restrict__ kG, const float* __restrict__ Wq_in,
    float* __restrict__ WK)
{
    const int bt0 = blockIdx.x * 32;
    const int r = blockIdx.y;
    __shared__ float ks[32][66];
    for (int e = threadIdx.x; e < 32 * 64; e += 256)
        ks[e >> 6][e & 63] = kG[(size_t)(bt0 + (e >> 6)) * DK + (e & 63)];
    __syncthreads();

    const int btl = threadIdx.x >> 3, hg = threadIdx.x & 7;
    const float* wq = Wq_in + (size_t)r * Hdim * DK;
    #pragma unroll 4
    for (int i = 0; i < 16; ++i) {
        int h = hg + i * 8;
        const float4* wr = (const float4*)(wq + (size_t)h * DK);
        float acc = 0.0f;
        #pragma unroll
        for (int d4 = 0; d4 < 16; ++d4) {
            float4 w = wr[d4];
            acc += w.x * ks[btl][d4 * 4] + w.y * ks[btl][d4 * 4 + 1]
                 + w.z * ks[btl][d4 * 4 + 2] + w.w * ks[btl][d4 * 4 + 3];
        }
        WK[((size_t)(bt0 + btl) * Rdim + r) * Hdim + h] = acc;
    }
}

// ---------------- Kernel 1e: fp16-pack hot weights {2 K x 4 cols per 16B} ----------------
// Wh_p  [r][d2<64][c4<128][8]   <- Wh_rnn [r][128][512]
// Wc_p  [r][d2<64][e4<96][8]    <- [Wq_c|Wk_c|Wv_c] [r][128][128] x3 (cols 0..383)
// Wo_p  [r][d2<64][c4<32][8]    <- Wout_c [r][128][128]
__global__ __launch_bounds__(256) void k_pack(
    const float* __restrict__ Wh_rnn,
    const float* __restrict__ Wq_c, const float* __restrict__ Wk_c,
    const float* __restrict__ Wv_c, const float* __restrict__ Wout_c,
    __half* __restrict__ Wh_p, __half* __restrict__ Wc_p, __half* __restrict__ Wo_p)
{
    const int NH = Rdim * 64 * 128 * 8;   // 393216
    const int NC = Rdim * 64 * 96 * 8;    // 294912
    const int NO = Rdim * 64 * 32 * 8;    // 98304
    int i = blockIdx.x * 256 + threadIdx.x;
    if (i < NH) {
        int j = i & 7, c4 = (i >> 3) & 127, d2 = (i >> 10) & 63, r = i >> 16;
        int d = 2 * d2 + (j >> 2), col = 4 * c4 + (j & 3);
        Wh_p[i] = __float2half(Wh_rnn[((size_t)r * Hdim + d) * 512 + col]);
    } else if (i < NH + NC) {
        int ii = i - NH;
        int j = ii & 7, e4 = (ii >> 3) % 96, d2 = (ii >> 3) / 96 % 64, r = ii / (64 * 96 * 8);
        int d = 2 * d2 + (j >> 2), col = 4 * e4 + (j & 3);
        int mId = col >> 7, colm = col & 127;
        const float* src = (mId == 0 ? Wq_c : (mId == 1 ? Wk_c : Wv_c));
        Wc_p[ii] = __float2half(src[((size_t)r * Hdim + d) * Hdim + colm]);
    } else if (i < NH + NC + NO) {
        int ii = i - NH - NC;
        int j = ii & 7, c4 = (ii >> 3) & 31, d2 = (ii >> 8) & 63, r = ii >> 14;
        int d = 2 * d2 + (j >> 2), col = 4 * c4 + (j & 3);
        Wo_p[ii] = __float2half(Wout_c[((size_t)r * Hdim + d) * Hdim + col]);
    }
}

// fp16x8 tile: unpack {d0:c0..c3, d1:c0..c3} and FMA into float4 acc
__device__ __forceinline__ void fma8(float4& acc, const __half2* h2, float hs0, float hs1) {
    float2 a0 = __half22float2(h2[0]);  // d0: c0,c1
    float2 a1 = __half22float2(h2[1]);  // d0: c2,c3
    float2 b0 = __half22float2(h2[2]);  // d1: c0,c1
    float2 b1 = __half22float2(h2[3]);  // d1: c2,c3
    acc.x += hs0 * a0.x + hs1 * b0.x;
    acc.y += hs0 * a0.y + hs1 * b0.y;
    acc.z += hs0 * a1.x + hs1 * b1.x;
    acc.w += hs0 * a1.y + hs1 * b1.y;
}

// ---------------- Kernel 2: sequential scan, one block per batch element ----------------
__global__ __launch_bounds__(768) void k_seq(
    const float* __restrict__ statics,
    const float* __restrict__ h0, const float* __restrict__ c0,
    const __half* __restrict__ Wh_p, const float* __restrict__ b_rnn,
    const __half* __restrict__ Wc_p, const __half* __restrict__ Wo_p,
    const float* __restrict__ W1, const float* __restrict__ b1,
    const float* __restrict__ W2, const float* __restrict__ b2,
    const float* __restrict__ ghG, const float* __restrict__ WK,
    const float* __restrict__ WB,
    const float* __restrict__ VX32, const __half* __restrict__ VX16, const int m16,
    const float* __restrict__ BX,
    float* __restrict__ out)
{
    const int b = blockIdx.x;
    const int tid = threadIdx.x;
    const int wave = tid >> 6, lane = tid & 63;

    __shared__ float hs[Rdim][Hdim], cs[Rdim][Hdim], hn[Rdim][Hdim], cn[Rdim][Hdim];
    __shared__ float pre_s[Rdim][4 * Hdim];
    __shared__ float qc[Rdim][Hdim], kc[Rdim][Hdim], vc[Rdim][Hdim], ctx_s[Rdim][Hdim];
    __shared__ float gh_s[Hdim];
    __shared__ float s0[Rdim], p0[Rdim], p1[Rdim], mk[Rdim];
    __shared__ float scs[HC][Rdim][Rdim], cps[HC][Rdim][Rdim];

    // init carry
    {
        int r = tid >> 7, j = tid & 127;
        hs[r][j] = h0[(size_t)b * 768 + tid];
        cs[r][j] = c0[(size_t)b * 768 + tid];
    }
    __syncthreads();

    for (int t = 0; t < Tdim; ++t) {
        const int bt = b * Tdim + t;

        // A: load gamma_h; decay hs
        if (tid < Hdim) gh_s[tid] = ghG[(size_t)bt * Hdim + tid];
        __syncthreads();
        {
            int r = tid >> 7, j = tid & 127;
            hs[r][j] *= gh_s[j];
        }
        __syncthreads();

        // B: s0/s1 via WK/WB dot over H (exact f32 -> top-k mask exact)
        if (wave < Rdim) {
            const int r = wave;
            const float* wk = WK + ((size_t)bt * Rdim + r) * Hdim;
            const float* wb = WB + r * Hdim;
            float hv0 = hs[r][lane], hv1 = hs[r][lane + 64];
            float a0 = hv0 * wk[lane] + hv1 * wk[lane + 64];
            float a1 = hv0 * wb[lane] + hv1 * wb[lane + 64];
            #pragma unroll
            for (int off = 32; off > 0; off >>= 1) {
                a0 += __shfl_xor(a0, off);
                a1 += __shfl_xor(a1, off);
            }
            if (lane == 0) {
                float sv0 = a0 * 0.125f, sv1 = a1 * 0.125f;
                s0[r] = sv0;
                float m = fmaxf(sv0, sv1);
                float e0 = expf(sv0 - m), e1 = expf(sv1 - m);
                float inv = 1.0f / (e0 + e1);
                p0[r] = e0 * inv; p1[r] = e1 * inv;
            }
        }
        __syncthreads();

        // C: top-k mask (stable tie-break like jax top_k)
        if (tid < Rdim) {
            int rank = 0;
            #pragma unroll
            for (int j = 0; j < Rdim; ++j)
                rank += (s0[j] > s0[tid] || (s0[j] == s0[tid] && j < tid)) ? 1 : 0;
            mk[tid] = (rank < KACT) ? 1.0f : 0.0f;
        }
        __syncthreads();

        // E: pre = p0*VX + p1*BX + b + hs@Wh (fp16-packed Wh, 64 x 16B loads)
        {
            int r = tid >> 7, e4 = tid & 127;
            int c0i = e4 * 4;
            float P0 = p0[r], P1 = p1[r];
            float4 bx = *(const float4*)(BX + r * 512 + c0i);
            float4 acc = *(const float4*)(b_rnn + r * 512 + c0i);
            if (m16) {
                const __half2* vp = (const __half2*)(VX16 + ((size_t)bt * Rdim + r) * 512 + c0i);
                float2 v01 = __half22float2(vp[0]), v23 = __half22float2(vp[1]);
                acc.x += P0 * v01.x + P1 * bx.x;
                acc.y += P0 * v01.y + P1 * bx.y;
                acc.z += P0 * v23.x + P1 * bx.z;
                acc.w += P0 * v23.y + P1 * bx.w;
            } else {
                float4 vx = *(const float4*)(VX32 + ((size_t)bt * Rdim + r) * 512 + c0i);
                acc.x += P0 * vx.x + P1 * bx.x;
                acc.y += P0 * vx.y + P1 * bx.y;
                acc.z += P0 * vx.z + P1 * bx.z;
                acc.w += P0 * vx.w + P1 * bx.w;
            }
            const __half2* wp = (const __half2*)(Wh_p + (((size_t)r * 64) * 128 + e4) * 8);
            #pragma unroll 8
            for (int d2 = 0; d2 < 64; ++d2) {
                fma8(acc, wp, hs[r][2 * d2], hs[r][2 * d2 + 1]);
                wp += 128 * 4;   // next d2 (128 c4-groups x 4 half2)
            }
            *(float4*)&pre_s[r][c0i] = acc;
        }
        __syncthreads();

        // F: LSTM elementwise
        {
            int r = tid >> 7, j = tid & 127;
            float ig = pre_s[r][j];
            float fg = pre_s[r][Hdim + j];
            float gg = pre_s[r][2 * Hdim + j];
            float og = pre_s[r][3 * Hdim + j];
            float cnew = sigmoidf_(fg) * cs[r][j] + sigmoidf_(ig) * tanhf(gg);
            float hnew = sigmoidf_(og) * tanhf(cnew);
            cn[r][j] = cnew;
            hn[r][j] = hnew;   // h_b == h_new in forward pass
        }
        __syncthreads();

        // G: qc/kc/vc = hn @ packed Wc (fp16), 576 threads x 4 cols
        if (tid < 576) {
            int r = tid / 96, e4 = tid % 96;
            float4 acc = make_float4(0.f, 0.f, 0.f, 0.f);
            const __half2* wp = (const __half2*)(Wc_p + (((size_t)r * 64) * 96 + e4) * 8);
            #pragma unroll 8
            for (int d2 = 0; d2 < 64; ++d2) {
                fma8(acc, wp, hn[r][2 * d2], hn[r][2 * d2 + 1]);
                wp += 96 * 4;
            }
            int col = e4 * 4, mId = col >> 7, colm = col & 127;
            float* dst = (mId == 0 ? &qc[r][colm] : (mId == 1 ? &kc[r][colm] : &vc[r][colm]));
            *(float4*)dst = acc;
        }
        __syncthreads();

        // H: attention scores over units (per head)
        if (tid < HC * Rdim * Rdim) {
            int h = tid / (Rdim * Rdim), rr = (tid / Rdim) % Rdim, ss = tid % Rdim;
            float acc = 0.0f;
            #pragma unroll 8
            for (int d = 0; d < CK; ++d) acc += qc[rr][h * CK + d] * kc[ss][h * CK + d];
            scs[h][rr][ss] = acc * 0.17677669529663687f;
        }
        __syncthreads();

        // I: softmax over s, times activation mask on r
        if (tid < HC * Rdim) {
            int h = tid / Rdim, rr = tid % Rdim;
            float m = scs[h][rr][0];
            #pragma unroll
            for (int ss = 1; ss < Rdim; ++ss) m = fmaxf(m, scs[h][rr][ss]);
            float e[Rdim], sum = 0.0f;
            #pragma unroll
            for (int ss = 0; ss < Rdim; ++ss) { e[ss] = expf(scs[h][rr][ss] - m); sum += e[ss]; }
            float inv = mk[rr] / sum;
            #pragma unroll
            for (int ss = 0; ss < Rdim; ++ss) cps[h][rr][ss] = e[ss] * inv;
        }
        __syncthreads();

        // J: ctx = cprobs @ vc
        {
            int r = tid >> 7, e = tid & 127, h = e >> 5;
            float acc = 0.0f;
            #pragma unroll
            for (int ss = 0; ss < Rdim; ++ss) acc += cps[h][r][ss] * vc[ss][e];
            ctx_s[r][e] = acc;
        }
        __syncthreads();

        // K: cs masked update + h_comm (packed fp16 Wout) & hs masked update
        {
            int r = tid >> 7, j = tid & 127;
            if (mk[r] > 0.5f) cs[r][j] = cn[r][j];
        }
        if (tid < 192) {
            int r = tid / 32, c4 = tid % 32;
            if (mk[r] > 0.5f) {
                float4 acc = make_float4(0.f, 0.f, 0.f, 0.f);
                const __half2* wp = (const __half2*)(Wo_p + (((size_t)r * 64) * 32 + c4) * 8);
                #pragma unroll 8
                for (int d2 = 0; d2 < 64; ++d2) {
                    fma8(acc, wp, ctx_s[r][2 * d2], ctx_s[r][2 * d2 + 1]);
                    wp += 32 * 4;
                }
                int col = c4 * 4;
                hs[r][col + 0] = acc.x + hn[r][col + 0];
                hs[r][col + 1] = acc.y + hn[r][col + 1];
                hs[r][col + 2] = acc.z + hn[r][col + 2];
                hs[r][col + 3] = acc.w + hn[r][col + 3];
            }
        }
        __syncthreads();
    }

    // Head: out[b] = (concat(hs, statics) @ W1 + b1) @ W2 + b2
    if (tid < 64) {
        float a = b1[tid];
        const float* hsf = &hs[0][0];
        #pragma unroll 4
        for (int i = 0; i < Rdim * Hdim; ++i) a += hsf[i] * W1[i * 64 + tid];
        #pragma unroll
        for (int i = 0; i < Sdim; ++i) a += statics[b * Sdim + i] * W1[(Rdim * Hdim + i) * 64 + tid];
        float pv = a * W2[tid];
        #pragma unroll
        for (int off = 32; off > 0; off >>= 1) pv += __shfl_xor(pv, off);
        if (tid == 0) out[b] = pv + b2[0];
    }
}

extern "C" void kernel_launch(void* const* d_in, const int* in_sizes, int n_in,
                              void* d_out, int out_size, void* d_ws, size_t ws_size,
                              hipStream_t stream) {
    const float* x       = (const float*)d_in[0];
    const float* statics = (const float*)d_in[1];
    const float* mask    = (const float*)d_in[2];
    const float* delta   = (const float*)d_in[3];
    const float* xlast   = (const float*)d_in[4];
    const float* xmean   = (const float*)d_in[5];
    const float* h0      = (const float*)d_in[6];
    const float* c0      = (const float*)d_in[7];
    const float* Wgx     = (const float*)d_in[8];
    const float* bgx     = (const float*)d_in[9];
    const float* Wgh     = (const float*)d_in[10];
    const float* bgh     = (const float*)d_in[11];
    const float* Wk_in   = (const float*)d_in[12];
    const float* bk_in   = (const float*)d_in[13];
    const float* Wv_in   = (const float*)d_in[14];
    const float* bv_in   = (const float*)d_in[15];
    const float* Wq_in   = (const float*)d_in[16];
    const float* Wx_rnn  = (const float*)d_in[17];
    const float* Wh_rnn  = (const float*)d_in[18];
    const float* b_rnn   = (const float*)d_in[19];
    const float* Wq_c    = (const float*)d_in[20];
    const float* Wk_c    = (const float*)d_in[21];
    const float* Wv_c    = (const float*)d_in[22];
    const float* Wout_c  = (const float*)d_in[23];
    const float* W1      = (const float*)d_in[24];
    const float* b1      = (const float*)d_in[25];
    const float* W2      = (const float*)d_in[26];
    const float* b2      = (const float*)d_in[27];

    const size_t nGh  = (size_t)Bdim * Tdim * Hdim;        // 1,179,648
    const size_t nK   = (size_t)Bdim * Tdim * DK;          //   786,432
    const size_t nV   = (size_t)Bdim * Tdim * DV;          // 1,572,864
    const size_t nBX  = (size_t)Rdim * 512;                //     3,072
    const size_t nWB  = (size_t)Rdim * Hdim;               //       768
    const size_t nWK  = (size_t)Bdim * Tdim * Rdim * Hdim; // 9,437,184
    const size_t nPck = (size_t)(393216 + 294912 + 98304) / 2;  // halves -> f32 slots (393,216)
    const size_t nVX  = (size_t)Bdim * Tdim * Rdim * 512;  // 37,748,736

    float*  ws   = (float*)d_ws;
    float*  ghG  = ws;
    float*  kG   = ghG + nGh;
    float*  vG   = kG + nK;
    float*  BX   = vG + nV;
    float*  WB   = BX + nBX;
    float*  WK   = WB + nWB;
    __half* Wh_p = (__half*)(WK + nWK);
    __half* Wc_p = Wh_p + 393216;
    __half* Wo_p = Wc_p + 294912;
    float*  VXf  = WK + nWK + nPck;
    __half* VXh  = (__half*)VXf;

    const size_t base = nGh + nK + nV + nBX + nWB + nWK + nPck;
    const int m16 = (ws_size >= (base + nVX) * sizeof(float)) ? 0 : 1;

    k_pre<<<dim3(Bdim * Tdim), dim3(128), 0, stream>>>(
        x, mask, delta, xlast, xmean, Wgx, bgx, Wgh, bgh,
        Wk_in, bk_in, Wv_in, bv_in, ghG, kG, vG);

    k_bx<<<dim3((Rdim * 512 + Rdim * Hdim + 255) / 256), dim3(256), 0, stream>>>(
        bv_in, Wx_rnn, bk_in, Wq_in, BX, WB);

    k_wk<<<dim3(Bdim * Tdim / 32, Rdim), dim3(256), 0, stream>>>(kG, Wq_in, WK);

    k_pack<<<dim3((393216 + 294912 + 98304 + 255) / 256), dim3(256), 0, stream>>>(
        Wh_rnn, Wq_c, Wk_c, Wv_c, Wout_c, Wh_p, Wc_p, Wo_p);

    k_vx<<<dim3(Bdim * Tdim / VX_BT, Rdim, 4), dim3(256), 0, stream>>>(
        vG, Wx_rnn, VXf, VXh, m16);

    k_seq<<<dim3(Bdim), dim3(768), 0, stream>>>(
        statics, h0, c0, Wh_p, b_rnn, Wc_p, Wo_p,
        W1, b1, W2, b2, ghG, WK, WB, VXf, VXh, m16, BX, (float*)d_out);
}

// Round 5
// 2582.758 us; speedup vs baseline: 1.5666x; 1.2855x over previous
//
#include <hip/hip_runtime.h>
#include <hip/hip_bf16.h>
#include <hip/hip_fp16.h>
#include <math.h>

#define Bdim 128
#define Tdim 96
#define Fdim 64
#define Sdim 16
#define Rdim 6
#define KACT 4
#define Hdim 128
#define DK 64
#define DV 128
#define HC 4
#define CK 32
#define CV 32

__device__ __forceinline__ float sigmoidf_(float x) { return 1.0f / (1.0f + expf(-x)); }

// ---------------- Kernel 1: precompute gamma_h, k, v for all (b,t) ----------------
__global__ __launch_bounds__(128) void k_pre(
    const float* __restrict__ x, const float* __restrict__ mask,
    const float* __restrict__ delta, const float* __restrict__ xlast,
    const float* __restrict__ xmean,
    const float* __restrict__ Wgx, const float* __restrict__ bgx,
    const float* __restrict__ Wgh, const float* __restrict__ bgh,
    const float* __restrict__ Wk, const float* __restrict__ bk,
    const float* __restrict__ Wv, const float* __restrict__ bv,
    float* __restrict__ ghO, float* __restrict__ kO, float* __restrict__ vO)
{
    const int bt = blockIdx.x;
    const int b = bt / Tdim, t = bt % Tdim;
    const int tid = threadIdx.x;
    __shared__ float d_s[Fdim], xh_s[Fdim];
    const int base = (b * Tdim + t) * Fdim;

    if (tid < Fdim) d_s[tid] = delta[base + tid];
    __syncthreads();

    if (tid < Fdim) {
        float z = bgx[tid];
        #pragma unroll 8
        for (int i = 0; i < Fdim; ++i) z += d_s[i] * Wgx[i * Fdim + tid];
        float gx = expf(-fmaxf(z, 0.0f));
        float m = mask[base + tid], xv = x[base + tid];
        float xl = xlast[base + tid], xm = xmean[b * Fdim + tid];
        xh_s[tid] = m * xv + (1.0f - m) * (gx * xl + (1.0f - gx) * xm);
    }
    {
        float z = bgh[tid];
        #pragma unroll 8
        for (int i = 0; i < Fdim; ++i) z += d_s[i] * Wgh[i * Hdim + tid];
        ghO[(size_t)(b * Tdim + t) * Hdim + tid] = expf(-fmaxf(z, 0.0f));
    }
    __syncthreads();

    if (tid < DK) {
        float z = bk[tid];
        #pragma unroll 8
        for (int j = 0; j < Fdim; ++j) z += xh_s[j] * Wk[j * DK + tid];
        kO[(size_t)(b * Tdim + t) * DK + tid] = z;
    }
    {
        float z = bv[tid];
        #pragma unroll 8
        for (int j = 0; j < Fdim; ++j) z += xh_s[j] * Wv[j * DV + tid];
        vO[(size_t)(b * Tdim + t) * DV + tid] = z;
    }
}

// ---------------- Kernel 1b: BX[r,c] = bv @ Wx_rnn[r];  WB[r,h] = Wq_in[r,h,:]·bk ----------------
__global__ __launch_bounds__(256) void k_bx(
    const float* __restrict__ bv, const float* __restrict__ Wx_rnn,
    const float* __restrict__ bk, const float* __restrict__ Wq_in,
    float* __restrict__ BX, float* __restrict__ WB)
{
    int c = blockIdx.x * 256 + threadIdx.x;
    if (c < Rdim * 512) {
        int r = c >> 9, cc = c & 511;
        float acc = 0.0f;
        #pragma unroll 4
        for (int d = 0; d < DV; ++d)
            acc += bv[d] * Wx_rnn[((size_t)r * DV + d) * 512 + cc];
        BX[c] = acc;
    } else if (c < Rdim * 512 + Rdim * Hdim) {
        int i = c - Rdim * 512;
        int r = i >> 7, h = i & 127;
        float acc = 0.0f;
        #pragma unroll 8
        for (int d = 0; d < DK; ++d)
            acc += Wq_in[((size_t)r * Hdim + h) * DK + d] * bk[d];
        WB[i] = acc;
    }
}

// ---------------- Kernel 1c: VX[b,t,r,c] = v[b,t,:] @ Wx_rnn[r][:,c] ----------------
#define VX_BT 32
__global__ __launch_bounds__(256) void k_vx(
    const float* __restrict__ vG, const float* __restrict__ Wx_rnn,
    float* __restrict__ VX32, __half* __restrict__ VX16, const int m16)
{
    const int bt0 = blockIdx.x * VX_BT;
    const int r = blockIdx.y;
    const int c = blockIdx.z * 128 + (threadIdx.x & 127);
    const int half = threadIdx.x >> 7;
    __shared__ float vv_s[VX_BT][DV];

    for (int i = threadIdx.x; i < VX_BT * DV; i += 256)
        vv_s[i >> 7][i & 127] = vG[(size_t)(bt0 + (i >> 7)) * DV + (i & 127)];
    __syncthreads();

    float acc[16];
    #pragma unroll
    for (int i = 0; i < 16; ++i) acc[i] = 0.0f;

    const float* wp = Wx_rnn + ((size_t)r * DV) * 512 + c;
    const int btb = half * 16;
    #pragma unroll 4
    for (int d = 0; d < DV; ++d) {
        float w = wp[(size_t)d * 512];
        #pragma unroll
        for (int i = 0; i < 16; ++i) acc[i] += vv_s[btb + i][d] * w;
    }
    #pragma unroll
    for (int i = 0; i < 16; ++i) {
        size_t idx = ((size_t)(bt0 + btb + i) * Rdim + r) * 512 + c;
        if (m16) VX16[idx] = __float2half(acc[i]);
        else     VX32[idx] = acc[i];
    }
}

// ---------------- Kernel 1d: WK[bt,r,h] = Wq_in[r,h,:] · k[bt,:] ----------------
__global__ __launch_bounds__(256) void k_wk(
    const float* __restrict__ kG, const float* __restrict__ Wq_in,
    float* __restrict__ WK)
{
    const int bt0 = blockIdx.x * 32;
    const int r = blockIdx.y;
    __shared__ float ks[32][66];
    for (int e = threadIdx.x; e < 32 * 64; e += 256)
        ks[e >> 6][e & 63] = kG[(size_t)(bt0 + (e >> 6)) * DK + (e & 63)];
    __syncthreads();

    const int btl = threadIdx.x >> 3, hg = threadIdx.x & 7;
    const float* wq = Wq_in + (size_t)r * Hdim * DK;
    #pragma unroll 4
    for (int i = 0; i < 16; ++i) {
        int h = hg + i * 8;
        const float4* wr = (const float4*)(wq + (size_t)h * DK);
        float acc = 0.0f;
        #pragma unroll
        for (int d4 = 0; d4 < 16; ++d4) {
            float4 w = wr[d4];
            acc += w.x * ks[btl][d4 * 4] + w.y * ks[btl][d4 * 4 + 1]
                 + w.z * ks[btl][d4 * 4 + 2] + w.w * ks[btl][d4 * 4 + 3];
        }
        WK[((size_t)(bt0 + btl) * Rdim + r) * Hdim + h] = acc;
    }
}

// ---------------- Kernel 1e: fp16-pack hot weights, {4 K x 4 cols} per 32B group ----------------
// Wh_p [r][d4<32][c4<128][16] <- Wh_rnn[r][128][512]
// Wc_p [r][d4<32][e4<96][16]  <- [Wq_c|Wk_c|Wv_c][r][128][128] (cols 0..383)
// Wo_p [r][d4<32][c4<32][16]  <- Wout_c[r][128][128]
// group idx j<16: d = 4*d4 + (j>>2), col = 4*c4 + (j&3)
#define NH_P (Rdim * 32 * 128 * 16)
#define NC_P (Rdim * 32 * 96 * 16)
#define NO_P (Rdim * 32 * 32 * 16)
__global__ __launch_bounds__(256) void k_pack(
    const float* __restrict__ Wh_rnn,
    const float* __restrict__ Wq_c, const float* __restrict__ Wk_c,
    const float* __restrict__ Wv_c, const float* __restrict__ Wout_c,
    __half* __restrict__ Wh_p, __half* __restrict__ Wc_p, __half* __restrict__ Wo_p)
{
    int i = blockIdx.x * 256 + threadIdx.x;
    if (i < NH_P) {
        int j = i & 15, t1 = i >> 4;
        int c4 = t1 & 127, t2 = t1 >> 7;
        int d4 = t2 & 31, r = t2 >> 5;
        int d = 4 * d4 + (j >> 2), col = 4 * c4 + (j & 3);
        Wh_p[i] = __float2half(Wh_rnn[((size_t)r * Hdim + d) * 512 + col]);
    } else if (i < NH_P + NC_P) {
        int ii = i - NH_P;
        int j = ii & 15, t1 = ii >> 4;
        int e4 = t1 % 96, t2 = t1 / 96;
        int d4 = t2 & 31, r = t2 >> 5;
        int d = 4 * d4 + (j >> 2), col = 4 * e4 + (j & 3);
        int mId = col >> 7, colm = col & 127;
        const float* src = (mId == 0 ? Wq_c : (mId == 1 ? Wk_c : Wv_c));
        Wc_p[ii] = __float2half(src[((size_t)r * Hdim + d) * Hdim + colm]);
    } else if (i < NH_P + NC_P + NO_P) {
        int ii = i - NH_P - NC_P;
        int j = ii & 15, t1 = ii >> 4;
        int c4 = t1 & 31, t2 = t1 >> 5;
        int d4 = t2 & 31, r = t2 >> 5;
        int d = 4 * d4 + (j >> 2), col = 4 * c4 + (j & 3);
        Wo_p[ii] = __float2half(Wout_c[((size_t)r * Hdim + d) * Hdim + col]);
    }
}

// 16 MACs: 4 K-values (hq) x 4 cols, weights as 16 halves (two 16B loads)
__device__ __forceinline__ void fma16(float4& acc, const __half* w, const float4 hq) {
    float4 wa = *(const float4*)(w);
    float4 wb = *(const float4*)(w + 8);
    const __half2* ha = (const __half2*)&wa;
    const __half2* hb = (const __half2*)&wb;
    float2 c;
    c = __half22float2(ha[0]); acc.x += hq.x * c.x; acc.y += hq.x * c.y;
    c = __half22float2(ha[1]); acc.z += hq.x * c.x; acc.w += hq.x * c.y;
    c = __half22float2(ha[2]); acc.x += hq.y * c.x; acc.y += hq.y * c.y;
    c = __half22float2(ha[3]); acc.z += hq.y * c.x; acc.w += hq.y * c.y;
    c = __half22float2(hb[0]); acc.x += hq.z * c.x; acc.y += hq.z * c.y;
    c = __half22float2(hb[1]); acc.z += hq.z * c.x; acc.w += hq.z * c.y;
    c = __half22float2(hb[2]); acc.x += hq.w * c.x; acc.y += hq.w * c.y;
    c = __half22float2(hb[3]); acc.z += hq.w * c.x; acc.w += hq.w * c.y;
}

// ---------------- Kernel 2: sequential scan, one block per batch, 5 barriers/step ----------------
__global__ __launch_bounds__(768) void k_seq(
    const float* __restrict__ statics,
    const float* __restrict__ h0, const float* __restrict__ c0,
    const __half* __restrict__ Wh_p, const __half* __restrict__ Wc_p,
    const __half* __restrict__ Wo_p,
    const float* __restrict__ b_rnn,
    const float* __restrict__ W1, const float* __restrict__ b1,
    const float* __restrict__ W2, const float* __restrict__ b2,
    const float* __restrict__ ghG, const float* __restrict__ WK,
    const float* __restrict__ WB,
    const float* __restrict__ VX32, const __half* __restrict__ VX16, const int m16,
    const float* __restrict__ BX,
    float* __restrict__ out)
{
    const int b = blockIdx.x;
    const int tid = threadIdx.x;
    const int wave = tid >> 6, lane = tid & 63;
    const int r_ = tid >> 7, j_ = tid & 127;

    __shared__ float hs[Rdim][Hdim], cs[Rdim][Hdim], hn[Rdim][Hdim], cn[Rdim][Hdim];
    __shared__ float pre_s[Rdim][4 * Hdim];
    __shared__ float qc[Rdim][Hdim], kc[Rdim][Hdim], vc[Rdim][Hdim], ctx[Rdim][Hdim];
    __shared__ float BX_s[Rdim][512], brnn_s[Rdim][512];
    __shared__ float WB_s[Rdim][Hdim];
    __shared__ float s0[8], p0[8], p1[8], mk[8];

    // preload per-model constants into LDS (once)
    ((float4*)&BX_s[0][0])[tid]   = ((const float4*)BX)[tid];
    ((float4*)&brnn_s[0][0])[tid] = ((const float4*)b_rnn)[tid];
    (&WB_s[0][0])[tid] = WB[tid];

    // register prefetch for t=0
    int bt = b * Tdim;
    float ghr = ghG[(size_t)bt * Hdim + j_];
    float vxr0, vxr1, vxr2, vxr3;
    {
        const size_t vb = ((size_t)bt * Rdim + r_) * 512 + j_;
        if (m16) {
            vxr0 = __half2float(VX16[vb]);       vxr1 = __half2float(VX16[vb + 128]);
            vxr2 = __half2float(VX16[vb + 256]); vxr3 = __half2float(VX16[vb + 384]);
        } else {
            vxr0 = VX32[vb];       vxr1 = VX32[vb + 128];
            vxr2 = VX32[vb + 256]; vxr3 = VX32[vb + 384];
        }
    }
    float wk0 = 0.0f, wk1 = 0.0f;
    if (wave < Rdim) {
        wk0 = WK[((size_t)bt * Rdim + wave) * Hdim + lane];
        wk1 = WK[((size_t)bt * Rdim + wave) * Hdim + lane + 64];
    }

    // init carry with decay(t=0) folded in
    hs[r_][j_] = h0[(size_t)b * 768 + tid] * ghr;
    cs[r_][j_] = c0[(size_t)b * 768 + tid];
    __syncthreads();

    for (int t = 0; t < Tdim; ++t) {
        bt = b * Tdim + t;
        const bool lastt = (t == Tdim - 1);

        // ==== phase 1: B scores (waves 0-5) in parallel with E = hs @ Wh (all waves)
        if (wave < Rdim) {
            float hv0 = hs[wave][lane], hv1 = hs[wave][lane + 64];
            float a0 = hv0 * wk0 + hv1 * wk1;
            float a1 = hv0 * WB_s[wave][lane] + hv1 * WB_s[wave][lane + 64];
            #pragma unroll
            for (int off = 32; off > 0; off >>= 1) {
                a0 += __shfl_xor(a0, off);
                a1 += __shfl_xor(a1, off);
            }
            if (lane == 0) {
                float sv0 = a0 * 0.125f, sv1 = a1 * 0.125f;
                s0[wave] = sv0;
                float m = fmaxf(sv0, sv1);
                float e0 = expf(sv0 - m), e1 = expf(sv1 - m);
                float inv = 1.0f / (e0 + e1);
                p0[wave] = e0 * inv; p1[wave] = e1 * inv;
            }
        }
        {
            float4 acc = make_float4(0.f, 0.f, 0.f, 0.f);
            const __half* wp = Wh_p + (((size_t)r_ * 32) * 128 + j_) * 16;
            #pragma unroll 8
            for (int d4 = 0; d4 < 32; ++d4) {
                float4 hq = *(const float4*)&hs[r_][d4 * 4];
                fma16(acc, wp, hq);
                wp += 128 * 16;
            }
            *(float4*)&pre_s[r_][j_ * 4] = acc;
        }
        __syncthreads();

        // ==== phase 2: top-k mask (6 thr) + LSTM with fused bias/VX/BX (all)
        if (tid < Rdim) {
            int rank = 0;
            #pragma unroll
            for (int j = 0; j < Rdim; ++j)
                rank += (s0[j] > s0[tid] || (s0[j] == s0[tid] && j < tid)) ? 1 : 0;
            mk[tid] = (rank < KACT) ? 1.0f : 0.0f;
        }
        {
            float P0 = p0[r_], P1 = p1[r_];
            float ig = pre_s[r_][j_]       + P0 * vxr0 + P1 * BX_s[r_][j_]       + brnn_s[r_][j_];
            float fg = pre_s[r_][128 + j_] + P0 * vxr1 + P1 * BX_s[r_][128 + j_] + brnn_s[r_][128 + j_];
            float gg = pre_s[r_][256 + j_] + P0 * vxr2 + P1 * BX_s[r_][256 + j_] + brnn_s[r_][256 + j_];
            float og = pre_s[r_][384 + j_] + P0 * vxr3 + P1 * BX_s[r_][384 + j_] + brnn_s[r_][384 + j_];
            float cnew = sigmoidf_(fg) * cs[r_][j_] + sigmoidf_(ig) * tanhf(gg);
            float hnew = sigmoidf_(og) * tanhf(cnew);
            cn[r_][j_] = cnew;
            hn[r_][j_] = hnew;
        }
        __syncthreads();

        // ==== phase 3: register-prefetch t+1 (all) + G qkv matvec (576 thr)
        if (!lastt) {
            const int bt1 = bt + 1;
            ghr = ghG[(size_t)bt1 * Hdim + j_];
            const size_t vb = ((size_t)bt1 * Rdim + r_) * 512 + j_;
            if (m16) {
                vxr0 = __half2float(VX16[vb]);       vxr1 = __half2float(VX16[vb + 128]);
                vxr2 = __half2float(VX16[vb + 256]); vxr3 = __half2float(VX16[vb + 384]);
            } else {
                vxr0 = VX32[vb];       vxr1 = VX32[vb + 128];
                vxr2 = VX32[vb + 256]; vxr3 = VX32[vb + 384];
            }
            if (wave < Rdim) {
                wk0 = WK[((size_t)bt1 * Rdim + wave) * Hdim + lane];
                wk1 = WK[((size_t)bt1 * Rdim + wave) * Hdim + lane + 64];
            }
        } else {
            ghr = 1.0f;
        }
        if (tid < 576) {
            int rG = tid / 96, e4 = tid % 96;
            float4 acc = make_float4(0.f, 0.f, 0.f, 0.f);
            const __half* wp = Wc_p + (((size_t)rG * 32) * 96 + e4) * 16;
            #pragma unroll 8
            for (int d4 = 0; d4 < 32; ++d4) {
                float4 hq = *(const float4*)&hn[rG][d4 * 4];
                fma16(acc, wp, hq);
                wp += 96 * 16;
            }
            int col = e4 * 4, mId = col >> 7, colm = col & 127;
            float* dst = (mId == 0 ? &qc[rG][colm] : (mId == 1 ? &kc[rG][colm] : &vc[rG][colm]));
            *(float4*)dst = acc;
        }
        __syncthreads();

        // ==== phase 4: fused attention scores + softmax + ctx (96 thr, all in regs)
        if (tid < 96) {
            int rr = tid >> 4, h = (tid >> 2) & 3, q = tid & 3;
            float4 Q[8];
            #pragma unroll
            for (int i = 0; i < 8; ++i) Q[i] = *(const float4*)&qc[rr][h * 32 + 4 * i];
            float sc[Rdim];
            #pragma unroll
            for (int ss = 0; ss < Rdim; ++ss) {
                float acc = 0.0f;
                #pragma unroll
                for (int i = 0; i < 8; ++i) {
                    float4 kq = *(const float4*)&kc[ss][h * 32 + 4 * i];
                    acc += Q[i].x * kq.x + Q[i].y * kq.y + Q[i].z * kq.z + Q[i].w * kq.w;
                }
                sc[ss] = acc * 0.17677669529663687f;
            }
            float m = sc[0];
            #pragma unroll
            for (int ss = 1; ss < Rdim; ++ss) m = fmaxf(m, sc[ss]);
            float e[Rdim], sum = 0.0f;
            #pragma unroll
            for (int ss = 0; ss < Rdim; ++ss) { e[ss] = expf(sc[ss] - m); sum += e[ss]; }
            float w = mk[rr] / sum;
            float4 a0 = make_float4(0.f, 0.f, 0.f, 0.f), a1 = a0;
            #pragma unroll
            for (int ss = 0; ss < Rdim; ++ss) {
                float cl = e[ss] * w;
                float4 v0 = *(const float4*)&vc[ss][h * 32 + q * 8];
                float4 v1 = *(const float4*)&vc[ss][h * 32 + q * 8 + 4];
                a0.x += cl * v0.x; a0.y += cl * v0.y; a0.z += cl * v0.z; a0.w += cl * v0.w;
                a1.x += cl * v1.x; a1.y += cl * v1.y; a1.z += cl * v1.z; a1.w += cl * v1.w;
            }
            *(float4*)&ctx[rr][h * 32 + q * 8] = a0;
            *(float4*)&ctx[rr][h * 32 + q * 8 + 4] = a1;
        }
        __syncthreads();

        // ==== phase 5: Wout matvec + state update + decay(t+1) folded in
        if (tid < 192) {
            int rK = tid / 32, c4 = tid % 32;
            if (mk[rK] > 0.5f) {
                float4 acc = make_float4(0.f, 0.f, 0.f, 0.f);
                const __half* wp = Wo_p + (((size_t)rK * 32) * 32 + c4) * 16;
                #pragma unroll 8
                for (int d4 = 0; d4 < 32; ++d4) {
                    float4 cq = *(const float4*)&ctx[rK][d4 * 4];
                    fma16(acc, wp, cq);
                    wp += 32 * 16;
                }
                float4 hq = *(const float4*)&hn[rK][c4 * 4];
                float4 g4 = make_float4(1.f, 1.f, 1.f, 1.f);
                if (!lastt) g4 = *(const float4*)&ghG[(size_t)(bt + 1) * Hdim + c4 * 4];
                float4 o;
                o.x = (acc.x + hq.x) * g4.x;
                o.y = (acc.y + hq.y) * g4.y;
                o.z = (acc.z + hq.z) * g4.z;
                o.w = (acc.w + hq.w) * g4.w;
                *(float4*)&hs[rK][c4 * 4] = o;
            }
        }
        {
            if (mk[r_] > 0.5f) cs[r_][j_] = cn[r_][j_];
            else               hs[r_][j_] *= ghr;   // inactive row: keep decayed h_old
        }
        __syncthreads();
    }

    // Head: out[b] = (concat(hs, statics) @ W1 + b1) @ W2 + b2
    if (tid < 64) {
        float a = b1[tid];
        const float* hsf = &hs[0][0];
        #pragma unroll 4
        for (int i = 0; i < Rdim * Hdim; ++i) a += hsf[i] * W1[i * 64 + tid];
        #pragma unroll
        for (int i = 0; i < Sdim; ++i) a += statics[b * Sdim + i] * W1[(Rdim * Hdim + i) * 64 + tid];
        float pv = a * W2[tid];
        #pragma unroll
        for (int off = 32; off > 0; off >>= 1) pv += __shfl_xor(pv, off);
        if (tid == 0) out[b] = pv + b2[0];
    }
}

extern "C" void kernel_launch(void* const* d_in, const int* in_sizes, int n_in,
                              void* d_out, int out_size, void* d_ws, size_t ws_size,
                              hipStream_t stream) {
    const float* x       = (const float*)d_in[0];
    const float* statics = (const float*)d_in[1];
    const float* mask    = (const float*)d_in[2];
    const float* delta   = (const float*)d_in[3];
    const float* xlast   = (const float*)d_in[4];
    const float* xmean   = (const float*)d_in[5];
    const float* h0      = (const float*)d_in[6];
    const float* c0      = (const float*)d_in[7];
    const float* Wgx     = (const float*)d_in[8];
    const float* bgx     = (const float*)d_in[9];
    const float* Wgh     = (const float*)d_in[10];
    const float* bgh     = (const float*)d_in[11];
    const float* Wk_in   = (const float*)d_in[12];
    const float* bk_in   = (const float*)d_in[13];
    const float* Wv_in   = (const float*)d_in[14];
    const float* bv_in   = (const float*)d_in[15];
    const float* Wq_in   = (const float*)d_in[16];
    const float* Wx_rnn  = (const float*)d_in[17];
    const float* Wh_rnn  = (const float*)d_in[18];
    const float* b_rnn   = (const float*)d_in[19];
    const float* Wq_c    = (const float*)d_in[20];
    const float* Wk_c    = (const float*)d_in[21];
    const float* Wv_c    = (const float*)d_in[22];
    const float* Wout_c  = (const float*)d_in[23];
    const float* W1      = (const float*)d_in[24];
    const float* b1      = (const float*)d_in[25];
    const float* W2      = (const float*)d_in[26];
    const float* b2      = (const float*)d_in[27];

    const size_t nGh  = (size_t)Bdim * Tdim * Hdim;        // 1,179,648
    const size_t nK   = (size_t)Bdim * Tdim * DK;          //   786,432
    const size_t nV   = (size_t)Bdim * Tdim * DV;          // 1,572,864
    const size_t nBX  = (size_t)Rdim * 512;                //     3,072
    const size_t nWB  = (size_t)Rdim * Hdim;               //       768
    const size_t nWK  = (size_t)Bdim * Tdim * Rdim * Hdim; // 9,437,184
    const size_t nPck = (size_t)(NH_P + NC_P + NO_P) / 2;  // halves -> f32 slots (393,216)
    const size_t nVX  = (size_t)Bdim * Tdim * Rdim * 512;  // 37,748,736

    float*  ws   = (float*)d_ws;
    float*  ghG  = ws;
    float*  kG   = ghG + nGh;
    float*  vG   = kG + nK;
    float*  BX   = vG + nV;
    float*  WB   = BX + nBX;
    float*  WK   = WB + nWB;
    __half* Wh_p = (__half*)(WK + nWK);
    __half* Wc_p = Wh_p + NH_P;
    __half* Wo_p = Wc_p + NC_P;
    float*  VXf  = WK + nWK + nPck;
    __half* VXh  = (__half*)VXf;

    const size_t base = nGh + nK + nV + nBX + nWB + nWK + nPck;
    const int m16 = (ws_size >= (base + nVX) * sizeof(float)) ? 0 : 1;

    k_pre<<<dim3(Bdim * Tdim), dim3(128), 0, stream>>>(
        x, mask, delta, xlast, xmean, Wgx, bgx, Wgh, bgh,
        Wk_in, bk_in, Wv_in, bv_in, ghG, kG, vG);

    k_bx<<<dim3((Rdim * 512 + Rdim * Hdim + 255) / 256), dim3(256), 0, stream>>>(
        bv_in, Wx_rnn, bk_in, Wq_in, BX, WB);

    k_wk<<<dim3(Bdim * Tdim / 32, Rdim), dim3(256), 0, stream>>>(kG, Wq_in, WK);

    k_pack<<<dim3((NH_P + NC_P + NO_P + 255) / 256), dim3(256), 0, stream>>>(
        Wh_rnn, Wq_c, Wk_c, Wv_c, Wout_c, Wh_p, Wc_p, Wo_p);

    k_vx<<<dim3(Bdim * Tdim / VX_BT, Rdim, 4), dim3(256), 0, stream>>>(
        vG, Wx_rnn, VXf, VXh, m16);

    k_seq<<<dim3(Bdim), dim3(768), 0, stream>>>(
        statics, h0, c0, Wh_p, Wc_p, Wo_p, b_rnn,
        W1, b1, W2, b2, ghG, WK, WB, VXf, VXh, m16, BX, (float*)d_out);
}